// Round 11
// baseline (57.178 us; speedup 1.0000x reference)
//
#include <hip/hip_runtime.h>
#include <hip/hip_bf16.h>

// ---- problem constants ----
#define BATCH 16
#define CIN   12
#define HIMG  512
#define WIMG  512
#define OCH   768
#define KDIM  256            // 16*16 patch
#define HW    (HIMG*WIMG)    // 262144
#define NPATCH 1024          // 32*32 patches per batch

#define MEAN_BLOCKS 4096     // BATCH*HW/4/256
#define PACK_BLOCKS 96       // OCH*KDIM/8/256

typedef __attribute__((ext_vector_type(8))) short short8;   // 8 bf16 = 4 VGPRs
typedef __attribute__((ext_vector_type(4))) float f32x4;

// ---------------------------------------------------------------------------
// Kernel A (merged): channel-mean (blocks 0..4095) + weight pack (4096..4191).
// mean: xm[b][h][w] = mean_c x[b][c][h][w], f32 -> bf16 (R1-validated body).
// pack: w f32 -> bf16 in MFMA fragment-lane order:
//   packed[u][0..7], u = (ot*8 + kk)*64 + lane holds
//   w[ot*16 + (lane&15)][kk*32 + (lane>>4)*8 + j], j=0..7.
// ---------------------------------------------------------------------------
__global__ __launch_bounds__(256) void mean_pack_kernel(
        const float* __restrict__ x, __hip_bfloat16* __restrict__ xm,
        const float* __restrict__ w, short8* __restrict__ wbp) {
    const int bid = blockIdx.x;
    if (bid < MEAN_BLOCKS) {
        int idx = bid * 256 + threadIdx.x;              // float4 index
        int b = idx >> 16;                              // 65536 float4 per image
        int pos = (idx & 65535) << 2;
        const float* px = x + (size_t)b * CIN * HW + pos;
        float sx = 0.f, sy = 0.f, sz = 0.f, sw = 0.f;
        #pragma unroll
        for (int c = 0; c < CIN; ++c) {
            f32x4 v = *reinterpret_cast<const f32x4*>(px + (size_t)c * HW);
            sx += v.x; sy += v.y; sz += v.z; sw += v.w;
        }
        const float inv = 1.0f / 12.0f;
        union { ushort4 u4; __hip_bfloat16 h[4]; } o;
        o.h[0] = __float2bfloat16(sx * inv);
        o.h[1] = __float2bfloat16(sy * inv);
        o.h[2] = __float2bfloat16(sz * inv);
        o.h[3] = __float2bfloat16(sw * inv);
        *reinterpret_cast<ushort4*>(xm + (size_t)idx * 4) = o.u4;
    } else {
        int u = (bid - MEAN_BLOCKS) * 256 + threadIdx.x;   // 0..24575
        int lane = u & 63;
        int kk   = (u >> 6) & 7;
        int ot   = u >> 9;                                 // 0..47
        int o = ot * 16 + (lane & 15);
        int k = kk * 32 + (lane >> 4) * 8;
        const float* src = w + (size_t)o * KDIM + k;
        f32x4 v0 = *reinterpret_cast<const f32x4*>(src);
        f32x4 v1 = *reinterpret_cast<const f32x4*>(src + 4);
        union { short8 s; __hip_bfloat16 h[8]; } t;
        t.h[0] = __float2bfloat16(v0.x);
        t.h[1] = __float2bfloat16(v0.y);
        t.h[2] = __float2bfloat16(v0.z);
        t.h[3] = __float2bfloat16(v0.w);
        t.h[4] = __float2bfloat16(v1.x);
        t.h[5] = __float2bfloat16(v1.y);
        t.h[6] = __float2bfloat16(v1.z);
        t.h[7] = __float2bfloat16(v1.w);
        wbp[u] = t.s;
    }
}

// ---------------------------------------------------------------------------
// Kernel B: patch-embedding GEMM, 512 blocks x 512 threads (8 waves).
// Block = (m-tile mt, o-quarter ot): 128 patches x 192 o-channels.
//   Weight re-read per block = 96 KB; total weight L2 traffic 49 MB
//   (half of R8's 98 MB).  blockIdx = mt*4 + ot -> XCD x serves a single
//   o-quarter (96 KB, per-XCD-L2-resident).
// 8 waves as 2(o) x 4(m): wave owns 96 o (6 frags) x 32 m (2 frags),
// acc[6][2] = 48 VGPR, K = 256 in 8 steps.
// Phase 1: copy 64 image rows x 512 cols of xm (128 KB bf16) into LDS tile
//   Bl[m = si*32+j][k = r*16+s]   (8 short8 per thread).
// Phase 2: A-fragments stream from packed weights (coalesced 1 KiB wave
//   loads), B-fragments from LDS (row stride 528 B -> 2-way max, free).
// ---------------------------------------------------------------------------
#define LDB 264   // 256 + 8 pad

__global__ __launch_bounds__(512, 4) void gemm_kernel(
        const short8* __restrict__ wbp,          // packed weights
        const __hip_bfloat16* __restrict__ xm,   // [B][H][W] mean image
        const float* __restrict__ bias,
        float* __restrict__ out) {               // [B][O][32][32]
    __shared__ short Bl[128][LDB];               // 67.6 KB -> 2 blocks/CU

    const int tid = threadIdx.x;
    const int mt = blockIdx.x >> 2;          // 0..127 m-tile (128 patches)
    const int ot = blockIdx.x & 3;           // o-quarter (192 channels)
    const int b  = mt >> 3;                  // 8 m-tiles per batch
    const int sq = mt & 7;                   // stripe quad (4 patch rows)

    // ---- phase 1: 64 image rows x 512 cols bf16 -> LDS (8 short8/thread) ----
    {
        const __hip_bfloat16* xb = xm + (size_t)b * HW + (size_t)(sq * 64) * WIMG;
        #pragma unroll
        for (int it = 0; it < 8; ++it) {
            const int g   = it * 512 + tid;  // granule 0..4095 (16 B each)
            const int r   = g >> 6;          // image row 0..63
            const int c   = g & 63;          // col granule (8 bf16 each)
            const int si  = r >> 4;          // stripe within quad
            const int r16 = r & 15;          // k-row within patch
            *reinterpret_cast<short8*>(
                &Bl[si * 32 + (c >> 1)][r16 * 16 + (c & 1) * 8]) =
                *reinterpret_cast<const short8*>(
                    reinterpret_cast<const short*>(xb + (size_t)r * WIMG) + c * 8);
        }
    }
    __syncthreads();

    // ---- phase 2: MFMA ----
    const int lane = tid & 63;
    const int wv   = tid >> 6;           // 0..7
    const int wo   = wv >> 2;            // 0..1  o-row of wave grid
    const int wm   = wv & 3;             // 0..3  m-col of wave grid
    const int lrow = lane & 15;
    const int lg   = lane >> 4;

    f32x4 acc[6][2] = {};
    // weight 16-row tile base: (ot*192 + wo*96)/16 = ot*12 + wo*6
    const short8* wp = wbp + (size_t)(ot * 12 + wo * 6) * 8 * 64 + lane;

    #pragma unroll
    for (int kk = 0; kk < 8; ++kk) {
        short8 af[6], bf[2];
        #pragma unroll
        for (int fo = 0; fo < 6; ++fo)
            af[fo] = wp[(size_t)(fo * 8 + kk) * 64];
        #pragma unroll
        for (int fm = 0; fm < 2; ++fm)
            bf[fm] = *reinterpret_cast<const short8*>(
                &Bl[wm * 32 + fm * 16 + lrow][kk * 32 + lg * 8]);
        #pragma unroll
        for (int fo = 0; fo < 6; ++fo)
            #pragma unroll
            for (int fm = 0; fm < 2; ++fm)
                acc[fo][fm] = __builtin_amdgcn_mfma_f32_16x16x32_bf16(af[fo], bf[fm], acc[fo][fm], 0, 0, 0);
    }

    // ---- epilogue: D row = o ((lane>>4)*4 + reg), col = m (lane&15) ----
    float* ob = out + (size_t)b * OCH * NPATCH + sq * 128 + wm * 32;
    #pragma unroll
    for (int fo = 0; fo < 6; ++fo) {
        const int obase = ot * 192 + wo * 96 + fo * 16 + lg * 4;
        #pragma unroll
        for (int r = 0; r < 4; ++r) {
            const int o = obase + r;
            const float bv = bias[o];
            float* orow = ob + (size_t)o * NPATCH;
            #pragma unroll
            for (int fm = 0; fm < 2; ++fm)
                orow[fm * 16 + lrow] = acc[fo][fm][r] + bv;
        }
    }
}

// ---------------------------------------------------------------------------
extern "C" void kernel_launch(void* const* d_in, const int* in_sizes, int n_in,
                              void* d_out, int out_size, void* d_ws, size_t ws_size,
                              hipStream_t stream) {
    const float* x    = (const float*)d_in[0];
    const float* w    = (const float*)d_in[1];
    const float* bias = (const float*)d_in[2];
    float* out = (float*)d_out;

    __hip_bfloat16* xm = (__hip_bfloat16*)d_ws;                                   // 8 MiB
    short8* wbp = (short8*)((char*)d_ws + (size_t)BATCH * HW * 2);                // 384 KiB

    mean_pack_kernel<<<MEAN_BLOCKS + PACK_BLOCKS, 256, 0, stream>>>(x, xm, w, wbp);
    gemm_kernel<<<512, 512, 0, stream>>>(wbp, xm, bias, out);
}

// Round 12
// 51.531 us; speedup vs baseline: 1.1096x; 1.1096x over previous
//
#include <hip/hip_runtime.h>
#include <hip/hip_bf16.h>

// ---- problem constants ----
#define BATCH 16
#define CIN   12
#define HIMG  512
#define WIMG  512
#define OCH   768
#define KDIM  256            // 16*16 patch
#define HW    (HIMG*WIMG)    // 262144
#define NPATCH 1024          // 32*32 patches per batch

#define MEAN_BLOCKS 4096     // BATCH*HW/4/256
#define PACK_BLOCKS 96       // OCH*KDIM/8/256

typedef __attribute__((ext_vector_type(8))) short short8;   // 8 bf16 = 4 VGPRs
typedef __attribute__((ext_vector_type(4))) float f32x4;

// ---------------------------------------------------------------------------
// Kernel A (merged): channel-mean (blocks 0..4095) + weight pack (4096..4191).
// mean: xm[b][h][w] = mean_c x[b][c][h][w], f32 -> bf16 (R1-validated body).
// pack: w f32 -> bf16 in MFMA fragment-lane order:
//   packed[u][0..7], u = (ot*8 + kk)*64 + lane holds
//   w[ot*16 + (lane&15)][kk*32 + (lane>>4)*8 + j], j=0..7.
// ---------------------------------------------------------------------------
__global__ __launch_bounds__(256) void mean_pack_kernel(
        const float* __restrict__ x, __hip_bfloat16* __restrict__ xm,
        const float* __restrict__ w, short8* __restrict__ wbp) {
    const int bid = blockIdx.x;
    if (bid < MEAN_BLOCKS) {
        int idx = bid * 256 + threadIdx.x;              // float4 index
        int b = idx >> 16;                              // 65536 float4 per image
        int pos = (idx & 65535) << 2;
        const float* px = x + (size_t)b * CIN * HW + pos;
        float sx = 0.f, sy = 0.f, sz = 0.f, sw = 0.f;
        #pragma unroll
        for (int c = 0; c < CIN; ++c) {
            f32x4 v = *reinterpret_cast<const f32x4*>(px + (size_t)c * HW);
            sx += v.x; sy += v.y; sz += v.z; sw += v.w;
        }
        const float inv = 1.0f / 12.0f;
        union { ushort4 u4; __hip_bfloat16 h[4]; } o;
        o.h[0] = __float2bfloat16(sx * inv);
        o.h[1] = __float2bfloat16(sy * inv);
        o.h[2] = __float2bfloat16(sz * inv);
        o.h[3] = __float2bfloat16(sw * inv);
        *reinterpret_cast<ushort4*>(xm + (size_t)idx * 4) = o.u4;
    } else {
        int u = (bid - MEAN_BLOCKS) * 256 + threadIdx.x;   // 0..24575
        int lane = u & 63;
        int kk   = (u >> 6) & 7;
        int ot   = u >> 9;                                 // 0..47
        int o = ot * 16 + (lane & 15);
        int k = kk * 32 + (lane >> 4) * 8;
        const float* src = w + (size_t)o * KDIM + k;
        f32x4 v0 = *reinterpret_cast<const f32x4*>(src);
        f32x4 v1 = *reinterpret_cast<const f32x4*>(src + 4);
        union { short8 s; __hip_bfloat16 h[8]; } t;
        t.h[0] = __float2bfloat16(v0.x);
        t.h[1] = __float2bfloat16(v0.y);
        t.h[2] = __float2bfloat16(v0.z);
        t.h[3] = __float2bfloat16(v0.w);
        t.h[4] = __float2bfloat16(v1.x);
        t.h[5] = __float2bfloat16(v1.y);
        t.h[6] = __float2bfloat16(v1.z);
        t.h[7] = __float2bfloat16(v1.w);
        wbp[u] = t.s;
    }
}

// ---------------------------------------------------------------------------
// Kernel B: patch-embedding GEMM, LDS-FREE.  512 blocks x 512 threads.
// Block = (batch b, stripe-PAIR sp, o-half oh): 64 patches x 384 o-channels.
// Wave wv owns o-range oh*384 + wv*48 (3 frags) x all 64 patches (4 frags),
// acc[3][4] = 48 VGPR, K = 256 in 8 steps.
//   A-fragments: coalesced 1 KiB wave loads from L2-resident packed weights.
//   B-fragments: DIRECT per-lane 16 B loads from L2/L3-resident xm — the
//     fragment layout (lane m = lane&15; r = kk*2+(lg>>1), s0 = (lg&1)*8)
//     is 8 contiguous bf16 in xm, so no LDS staging, no barrier.  Same
//     elements the R8 LDS reads produced: Bl[m][k] = xm[.., sp*32+si*16+r,
//     j*16+s].
// No __syncthreads anywhere -> compiler pipelines loads across the whole
// K-loop; 2 resident blocks/CU overlap freely.
// ---------------------------------------------------------------------------
__global__ __launch_bounds__(512, 4) void gemm_kernel(
        const short8* __restrict__ wbp,          // packed weights
        const __hip_bfloat16* __restrict__ xm,   // [B][H][W] mean image
        const float* __restrict__ bias,
        float* __restrict__ out) {               // [B][O][32][32]
    const int tid = threadIdx.x;
    const int b  = blockIdx.x >> 5;
    const int sp = (blockIdx.x >> 1) & 15;   // stripe pair (2 patch rows)
    const int oh = blockIdx.x & 1;           // o-half

    const int lane = tid & 63;
    const int wv   = tid >> 6;           // 0..7
    const int lrow = lane & 15;
    const int lg   = lane >> 4;

    // B base: b, stripe-pair, k-slice part from lg (row (lg>>1), col (lg&1)*8)
    const __hip_bfloat16* xmb = xm + (size_t)b * HW + sp * (32 * WIMG)
                                + (lg >> 1) * WIMG + (lg & 1) * 8;
    // per-fragment m offsets: m = fm*16 + lrow -> stripe si = m>>5, col j = m&31
    int e0[4];
    #pragma unroll
    for (int fm = 0; fm < 4; ++fm) {
        const int ml = fm * 16 + lrow;
        e0[fm] = (ml >> 5) * (16 * WIMG) + (ml & 31) * 16;
    }

    f32x4 acc[3][4] = {};
    // weight 16-row tile base: (oh*384 + wv*48)/16 = oh*24 + wv*3
    const short8* wp = wbp + (size_t)(oh * 24 + wv * 3) * 8 * 64 + lane;

    #pragma unroll
    for (int kk = 0; kk < 8; ++kk) {
        short8 af[3], bf[4];
        #pragma unroll
        for (int fo = 0; fo < 3; ++fo)
            af[fo] = wp[(size_t)(fo * 8 + kk) * 64];
        #pragma unroll
        for (int fm = 0; fm < 4; ++fm)
            bf[fm] = *reinterpret_cast<const short8*>(xmb + e0[fm] + kk * (2 * WIMG));
        #pragma unroll
        for (int fo = 0; fo < 3; ++fo)
            #pragma unroll
            for (int fm = 0; fm < 4; ++fm)
                acc[fo][fm] = __builtin_amdgcn_mfma_f32_16x16x32_bf16(af[fo], bf[fm], acc[fo][fm], 0, 0, 0);
    }

    // ---- epilogue: D row = o ((lane>>4)*4 + reg), col = m (lane&15) ----
    float* ob = out + (size_t)b * OCH * NPATCH + sp * 64;
    #pragma unroll
    for (int fo = 0; fo < 3; ++fo) {
        const int obase = oh * 384 + wv * 48 + fo * 16 + lg * 4;
        #pragma unroll
        for (int r = 0; r < 4; ++r) {
            const int o = obase + r;
            const float bv = bias[o];
            float* orow = ob + (size_t)o * NPATCH;
            #pragma unroll
            for (int fm = 0; fm < 4; ++fm)
                orow[fm * 16 + lrow] = acc[fo][fm][r] + bv;
        }
    }
}

// ---------------------------------------------------------------------------
extern "C" void kernel_launch(void* const* d_in, const int* in_sizes, int n_in,
                              void* d_out, int out_size, void* d_ws, size_t ws_size,
                              hipStream_t stream) {
    const float* x    = (const float*)d_in[0];
    const float* w    = (const float*)d_in[1];
    const float* bias = (const float*)d_in[2];
    float* out = (float*)d_out;

    __hip_bfloat16* xm = (__hip_bfloat16*)d_ws;                                   // 8 MiB
    short8* wbp = (short8*)((char*)d_ws + (size_t)BATCH * HW * 2);                // 384 KiB

    mean_pack_kernel<<<MEAN_BLOCKS + PACK_BLOCKS, 256, 0, stream>>>(x, xm, w, wbp);
    gemm_kernel<<<512, 512, 0, stream>>>(wbp, xm, bias, out);
}